// Round 10
// baseline (707.287 us; speedup 1.0000x reference)
//
#include <hip/hip_runtime.h>

typedef unsigned int u32;
typedef unsigned short u16;
typedef __bf16 bf16x8 __attribute__((ext_vector_type(8)));
typedef float f32x4 __attribute__((ext_vector_type(4)));
typedef float f32x2 __attribute__((ext_vector_type(2)));

// ---------- helpers ----------

__device__ __forceinline__ u16 f2bf(float f) {
  u32 u = __builtin_bit_cast(u32, f);
  u32 r = u + 0x7fffu + ((u >> 16) & 1u);  // RNE
  return (u16)(r >> 16);
}

__device__ __forceinline__ u32 cvtpk_bf16(float a, float b) {
  u32 d;
  asm("v_cvt_pk_bf16_f32 %0, %1, %2" : "=v"(d) : "v"(a), "v"(b));
  return d;  // lo = bf16(a), hi = bf16(b)
}

__device__ __forceinline__ void gload_lds16(const void* g, void* l) {
  __builtin_amdgcn_global_load_lds(
      (__attribute__((address_space(1))) void*)(g),
      (__attribute__((address_space(3))) void*)(l), 16, 0, 0);
}

// ---------- fp32 -> bf16 conversion (hs + 4 weights) ----------

__global__ __launch_bounds__(256) void convert_kernel(
    const float* __restrict__ hs, const float* __restrict__ wq,
    const float* __restrict__ wk, const float* __restrict__ wv,
    const float* __restrict__ wo,
    u16* __restrict__ hsb, u16* __restrict__ wqb, u16* __restrict__ wkb,
    u16* __restrict__ wvb, u16* __restrict__ wob) {
  long t = (long)blockIdx.x * 256 + threadIdx.x;
  const float* src;
  u16* dst;
  long off;
  if (t < 2097152) {
    src = hs; dst = hsb; off = t << 3;
  } else {
    long u = t - 2097152;
    int wi = (int)(u >> 19);
    off = (u & 524287) << 3;
    if (wi == 0)      { src = wq; dst = wqb; }
    else if (wi == 1) { src = wk; dst = wkb; }
    else if (wi == 2) { src = wv; dst = wvb; }
    else              { src = wo; dst = wob; }
  }
  float4 a = *(const float4*)(src + off);
  float4 b = *(const float4*)(src + off + 4);
  uint4 o;
  o.x = (u32)f2bf(a.x) | ((u32)f2bf(a.y) << 16);
  o.y = (u32)f2bf(a.z) | ((u32)f2bf(a.w) << 16);
  o.z = (u32)f2bf(b.x) | ((u32)f2bf(b.y) << 16);
  o.w = (u32)f2bf(b.z) | ((u32)f2bf(b.w) << 16);
  *(uint4*)(dst + off) = o;
}

// ---------- 256x256 GEMM, BK=64, 8 waves, read-ahead pipelined ----------
// (frozen: r5 schedule + r6 mapping v2)

template <int OF32>
__global__ __launch_bounds__(512, 2) void gemm256_kernel(
    const u16* __restrict__ A, const u16* __restrict__ Bw,
    const float* __restrict__ bias0, const float* __restrict__ bias1,
    const float* __restrict__ bias2, void* __restrict__ o0,
    void* __restrict__ o1, void* __restrict__ o2, int m_tiles, int n_tiles) {
  __shared__ __align__(16) char L[2][2][2][16384];  // [buf][op][khalf] 256r x 64B

  const int tid = threadIdx.x;
  const int lane = tid & 63, w = tid >> 6;
  const int lr = lane & 15, lk = lane >> 4;
  const int wm = (w >> 2) * 128, wn = (w & 3) * 64;

  const int bid = blockIdx.x;
  const int xcd = bid & 7, loc = bid >> 3;
  const int npx = n_tiles >> 3;
  const int n_idx = xcd * npx + loc % npx;
  const int m_idx = loc / npx;
  const int m0 = m_idx * 256, n0 = n_idx * 256;

  const char* Ab = (const char*)A;
  const char* Bb = (const char*)Bw;
  const char* gA[2];
  const char* gB[2];
#pragma unroll
  for (int j = 0; j < 2; j++) {
    const int o = j * 8192 + tid * 16;
    const int row = o >> 6;
    const int c = (o & 63) ^ (((row >> 1) & 3) << 4);
    gA[j] = Ab + (size_t)(m0 + row) * 4096 + c;
    gB[j] = Bb + (size_t)(n0 + row) * 4096 + c;
  }

  auto stage = [&](int t, int kh, int isB) {
    char* Ld = &L[t & 1][isB][kh][0] + tid * 16;
    const int gof = t * 128 + kh * 64;
#pragma unroll
    for (int j = 0; j < 2; j++)
      gload_lds16((isB ? gB[j] : gA[j]) + gof, Ld + j * 8192);
  };
  auto rdA = [&](bf16x8* dst, int buf, int kh, int mset) {
#pragma unroll
    for (int m = 0; m < 4; m++) {
      const int row = wm + mset * 64 + m * 16 + lr;
      const int c = (lk * 16) ^ (((row >> 1) & 3) << 4);
      dst[m] = *(const bf16x8*)(&L[buf][0][kh][0] + row * 64 + c);
    }
  };
  auto rdB = [&](bf16x8* dst, int buf, int kh) {
#pragma unroll
    for (int n = 0; n < 4; n++) {
      const int row = wn + n * 16 + lr;
      const int c = (lk * 16) ^ (((row >> 1) & 3) << 4);
      dst[n] = *(const bf16x8*)(&L[buf][1][kh][0] + row * 64 + c);
    }
  };

  f32x4 acc[2][4][4];
#pragma unroll
  for (int s = 0; s < 2; s++)
#pragma unroll
    for (int m = 0; m < 4; m++)
#pragma unroll
      for (int n = 0; n < 4; n++) acc[s][m][n] = {0.f, 0.f, 0.f, 0.f};

  auto mm = [&](f32x4 (&ac)[4][4], bf16x8* a_, bf16x8* b_) {
    __builtin_amdgcn_s_setprio(1);
#pragma unroll
    for (int m = 0; m < 4; m++)
#pragma unroll
      for (int n = 0; n < 4; n++)
        ac[m][n] = __builtin_amdgcn_mfma_f32_16x16x32_bf16(a_[m], b_[n],
                                                           ac[m][n], 0, 0, 0);
    __builtin_amdgcn_s_setprio(0);
  };

  // prologue: stage tile 0 fully (order kh0A, kh0B, kh1A, kh1B)
  stage(0, 0, 0); stage(0, 0, 1); stage(0, 1, 0); stage(0, 1, 1);

  bf16x8 aP[4], aQ[4], b0[4], b1[4];
  for (int t = 0; t < 32; ++t) {
    const int buf = t & 1;
    const int t1 = (t + 1 < 32) ? t + 1 : 31;
    // ===== segment A: {ph4(t-1) , ph1(t)} =====
    asm volatile("s_waitcnt vmcnt(4)" ::: "memory");  // publish (t,kh0,*)
    asm volatile("s_barrier" ::: "memory");
    rdA(aP, buf, 0, 0);            // ph1 operands
    rdB(b0, buf, 0);
    stage(t1, 0, 0);               // (t+1, kh0, A)
    if (t) mm(acc[1], aQ, b1);     // ph4(t-1): kh1 x mset1
    rdA(aQ, buf, 0, 1);            // ph2 operands
    stage(t1, 0, 1);               // (t+1, kh0, B)
    mm(acc[0], aP, b0);            // ph1: kh0 x mset0
    // ===== segment B: {ph2(t) , ph3(t)} =====
    asm volatile("s_waitcnt vmcnt(4)" ::: "memory");  // publish (t,kh1,*)
    asm volatile("s_barrier" ::: "memory");
    rdA(aP, buf, 1, 0);            // ph3 operands
    rdB(b1, buf, 1);
    stage(t1, 1, 0);               // (t+1, kh1, A)
    mm(acc[1], aQ, b0);            // ph2: kh0 x mset1
    rdA(aQ, buf, 1, 1);            // ph4 operands
    stage(t1, 1, 1);               // (t+1, kh1, B)
    mm(acc[0], aP, b1);            // ph3: kh1 x mset0
  }
  mm(acc[1], aQ, b1);              // ph4(31)

  // epilogue: bias + store
  const float* bias;
  void* op;
  int nl0;
  if (OF32) {
    bias = bias0; op = o0; nl0 = n0;
  } else {
    const int seg = n0 >> 11;
    bias = seg == 0 ? bias0 : (seg == 1 ? bias1 : bias2);
    op = seg == 0 ? o0 : (seg == 1 ? o1 : o2);
    nl0 = n0 & 2047;
  }
#pragma unroll
  for (int n = 0; n < 4; n++) {
    const int col = nl0 + wn + n * 16 + lr;
    const float bv = bias[col];
#pragma unroll
    for (int s = 0; s < 2; s++)
#pragma unroll
      for (int m = 0; m < 4; m++) {
        const int grow = m0 + wm + s * 64 + m * 16 + lk * 4;
#pragma unroll
        for (int r = 0; r < 4; r++) {
          const float v = acc[s][m][n][r] + bv;
          if (OF32)
            ((float*)op)[(size_t)(grow + r) * 2048 + col] = v;
          else
            ((u16*)op)[(size_t)(grow + r) * 2048 + col] = f2bf(v);
        }
      }
  }
}

// ---------- fused causal attention with alibi + tanh cap ----------
// v5: v4 pipeline + packed-fp32 softmax. All elementwise fp32 math shaped
// as float2 (targets v_pk_fma_f32 / v_pk_mul_f32 full-rate packed VALU);
// bf16 P-pack via v_cvt_pk_bf16_f32 (1 instr / 2 elems). exp2 stays scalar
// (transcendental). launch_bounds (512,4) pins VGPR<=128 -> 2 blocks/CU.

__global__ __launch_bounds__(512, 4) void attn_kernel(
    const u16* __restrict__ Qm, const u16* __restrict__ Km,
    const u16* __restrict__ Vm, const float* __restrict__ slopes,
    u16* __restrict__ ctx) {
  __shared__ __align__(16) char Ks[2][64 * 256];   // 32 KB, xor-swizzled rows
  __shared__ __align__(16) char Vt[128 * 128];     // 16 KB, V^T xor-swizzled
  __shared__ __align__(16) char Pb[8][16 * 128];   // 16 KB, per-wave P

  const int bid = blockIdx.x;
  const int sw = (bid & 7) * 64 + (bid >> 3);
  const int bh = sw >> 3, pi = sw & 7;
  const int b = bh >> 4, h = bh & 15;
  const int NTA = 2 * pi + 2;

  const int tid = threadIdx.x;
  const int lane = tid & 63, w = tid >> 6;
  const int lr = lane & 15, lk = lane >> 4;

  const char* Qb = (const char*)Qm + (size_t)b * 2048 * 4096 + h * 256;
  const char* Kb = (const char*)Km + (size_t)b * 2048 * 4096 + h * 256;
  const char* Vb = (const char*)Vm + (size_t)b * 2048 * 4096 + h * 256;

  const float SCALE = 0.08838834764831845f;  // 1/sqrt(128)
  const float sl_c = slopes[h] * SCALE;

  // odd poly for 30*tanh(z/30)*log2(e), |z|<=16
  const f32x2 C1v = {1.4426950408889634f, 1.4426950408889634f};
  const f32x2 C3v = {-5.343315e-4f, -5.343315e-4f};
  const f32x2 C5v = {2.374806e-7f, 2.374806e-7f};
  const f32x2 C7v = {-1.068005e-10f, -1.068005e-10f};
  const f32x2 SC2 = {SCALE, SCALE};
  const f32x2 NEG16 = {-16.0f, -16.0f};
  const f32x2 POS16 = {16.0f, 16.0f};

  // hoisted per-lane alibi offsets, paired over r: zo2[nb*2+p] for r=2p,2p+1
  f32x2 zo2[8];
#pragma unroll
  for (int nb = 0; nb < 4; nb++)
#pragma unroll
    for (int p = 0; p < 2; p++) {
      zo2[nb * 2 + p][0] = sl_c * (float)((lr - lk * 4) + nb * 16 - (2 * p));
      zo2[nb * 2 + p][1] = sl_c * (float)((lr - lk * 4) + nb * 16 - (2 * p + 1));
    }

  const int vd0 = (tid & 15) * 8;
  const int vkv2 = tid >> 4;

  uint4 vr0, vr1;

  auto kvt_of = [&](int it) { return it < NTA ? it : it - NTA; };

  auto stageK = [&](int it, int buf) {
    const int kv0 = kvt_of(it) * 64;
#pragma unroll
    for (int j = 0; j < 2; j++) {
      const int o = j * 8192 + tid * 16;
      const int row = o >> 8, c = (o & 255) ^ ((row & 7) << 4);
      gload_lds16(Kb + (size_t)(kv0 + row) * 4096 + c, Ks[buf] + o);
    }
  };
  auto loadV = [&](int it) {
    const int kv0 = kvt_of(it) * 64;
    vr0 = *(const uint4*)(Vb + (size_t)(kv0 + vkv2 * 2) * 4096 + vd0 * 2);
    vr1 = *(const uint4*)(Vb + (size_t)(kv0 + vkv2 * 2 + 1) * 4096 + vd0 * 2);
  };
  auto writeV = [&]() {
    const u32* p0 = (const u32*)&vr0;
    const u32* p1 = (const u32*)&vr1;
#pragma unroll
    for (int wd = 0; wd < 4; wd++) {
      const u32 ev = __builtin_amdgcn_perm(p1[wd], p0[wd], 0x05040100u);
      const u32 od = __builtin_amdgcn_perm(p1[wd], p0[wd], 0x07060302u);
      const int d0_ = vd0 + 2 * wd, d1_ = d0_ + 1;
      *(u32*)(Vt + d0_ * 128 +
              ((vkv2 * 4) ^ (((d0_ ^ (d0_ >> 3)) & 7) << 4))) = ev;
      *(u32*)(Vt + d1_ * 128 +
              ((vkv2 * 4) ^ (((d1_ ^ (d1_ >> 3)) & 7) << 4))) = od;
    }
  };

  bf16x8 qf[4];
  f32x4 pv[8];
  f32x2 rs2[2];
  int q0 = 0;

  stageK(0, 0);  // issued first (oldest in vmcnt FIFO)
  loadV(0);

  for (int it = 0; it < 34; ++it) {
    const int kb = it & 1;
    const int kv0 = kvt_of(it) * 64;

    if (it == 0 || it == NTA) {  // block-uniform: (re)load Q, reset acc
      const int st = (it == 0) ? pi : (15 - pi);
      q0 = st * 128 + w * 16;
#pragma unroll
      for (int kc = 0; kc < 4; kc++)
        qf[kc] =
            *(const bf16x8*)(Qb + (size_t)(q0 + lr) * 4096 + kc * 64 + lk * 16);
#pragma unroll
      for (int i = 0; i < 8; i++) pv[i] = {0.f, 0.f, 0.f, 0.f};
      rs2[0] = {0.f, 0.f};
      rs2[1] = {0.f, 0.f};
    }

    __syncthreads();  // A: all waves done with PV(it-1) reads of Vt
    writeV();
    asm volatile("s_waitcnt vmcnt(0)" ::: "memory");
    __syncthreads();  // B: publish Vt + Ks[kb]

    if (it + 1 < 34) {      // prefetch: K stage (full iter of flight) + V regs
      stageK(it + 1, kb ^ 1);
      loadV(it + 1);
    }

    // S = Q K^T   (reads Ks[kb])
    f32x4 sc[4];
    __builtin_amdgcn_s_setprio(1);
#pragma unroll
    for (int nb = 0; nb < 4; nb++) {
      f32x4 a = {0.f, 0.f, 0.f, 0.f};
      const int krow = nb * 16 + lr;
#pragma unroll
      for (int kc = 0; kc < 4; kc++) {
        const int off = krow * 256 + ((kc * 64 + lk * 16) ^ ((krow & 7) << 4));
        bf16x8 kf = *(const bf16x8*)(Ks[kb] + off);
        a = __builtin_amdgcn_mfma_f32_16x16x32_bf16(qf[kc], kf, a, 0, 0, 0);
      }
      sc[nb] = a;
    }
    __builtin_amdgcn_s_setprio(0);

    // softmax: packed-fp32 math, one exp2/element, mask only diagonal tiles
    const bool diag = (it < NTA) ? (it >= NTA - 2) : (it >= 32);
    const float sb = sl_c * (float)(kv0 - q0);
    const f32x2 sb2 = {sb, sb};
#pragma unroll
    for (int nb = 0; nb < 4; nb++) {
#pragma unroll
      for (int p = 0; p < 2; p++) {
        f32x2 s2 = {sc[nb][2 * p], sc[nb][2 * p + 1]};
        f32x2 z = __builtin_elementwise_fma(s2, SC2, zo2[nb * 2 + p] + sb2);
        z = __builtin_elementwise_max(z, NEG16);
        z = __builtin_elementwise_min(z, POS16);
        const f32x2 u2 = z * z;
        f32x2 hh = __builtin_elementwise_fma(u2, C7v, C5v);
        hh = __builtin_elementwise_fma(u2, hh, C3v);
        hh = __builtin_elementwise_fma(u2, hh, C1v);
        const f32x2 ee = z * hh;
        float p0 = exp2f(ee[0]);
        float p1 = exp2f(ee[1]);
        if (diag) {
          const int kv = kv0 + nb * 16 + lr;
          const int qA = q0 + lk * 4 + 2 * p;
          p0 = (kv <= qA) ? p0 : 0.0f;
          p1 = (kv <= qA + 1) ? p1 : 0.0f;
        }
        f32x2 pr = {p0, p1};
        rs2[p] += pr;
        const u32 pk = cvtpk_bf16(p0, p1);
        const int qq0 = lk * 4 + 2 * p;
        const int qq1 = qq0 + 1;
        const int off0 = qq0 * 128 + (((nb * 16 + lr) * 2) ^ ((qq0 & 7) << 4));
        const int off1 = qq1 * 128 + (((nb * 16 + lr) * 2) ^ ((qq1 & 7) << 4));
        *(u16*)(Pb[w] + off0) = (u16)pk;
        *(u16*)(Pb[w] + off1) = (u16)(pk >> 16);
      }
    }

    // ctx += P V   (reads Vt; closed by next iter's barrier A)
    __builtin_amdgcn_s_setprio(1);
#pragma unroll
    for (int kc = 0; kc < 2; kc++) {
      const int poff = lr * 128 + ((kc * 64 + lk * 16) ^ ((lr & 7) << 4));
      bf16x8 pf = *(const bf16x8*)(Pb[w] + poff);
#pragma unroll
      for (int db = 0; db < 8; db++) {
        const int d = db * 16 + lr;
        const int voff =
            d * 128 + ((kc * 64 + lk * 16) ^ (((d ^ (d >> 3)) & 7) << 4));
        bf16x8 vf = *(const bf16x8*)(Vt + voff);
        pv[db] = __builtin_amdgcn_mfma_f32_16x16x32_bf16(pf, vf, pv[db], 0, 0, 0);
      }
    }
    __builtin_amdgcn_s_setprio(0);

    if (it == NTA - 1 || it == 33) {  // finalize current supertile
      float inv[4];
#pragma unroll
      for (int r = 0; r < 4; r++) {
        float s = (r < 2) ? rs2[0][r & 1] : rs2[1][r & 1];
        s += __shfl_xor(s, 1);
        s += __shfl_xor(s, 2);
        s += __shfl_xor(s, 4);
        s += __shfl_xor(s, 8);
        inv[r] = 1.0f / s;
      }
      const size_t baserow = (size_t)b * 2048 + q0 + lk * 4;
#pragma unroll
      for (int db = 0; db < 8; db++)
#pragma unroll
        for (int r = 0; r < 4; r++)
          ctx[(baserow + r) * 2048 + h * 128 + db * 16 + lr] =
              f2bf(pv[db][r] * inv[r]);
    }
  }
}

// ---------- launcher ----------

extern "C" void kernel_launch(void* const* d_in, const int* in_sizes, int n_in,
                              void* d_out, int out_size, void* d_ws,
                              size_t ws_size, hipStream_t stream) {
  const float* hs = (const float*)d_in[0];
  const float* Wq = (const float*)d_in[1];
  const float* bq = (const float*)d_in[2];
  const float* Wk = (const float*)d_in[3];
  const float* bk = (const float*)d_in[4];
  const float* Wv = (const float*)d_in[5];
  const float* bv = (const float*)d_in[6];
  const float* Wo = (const float*)d_in[7];
  const float* bo = (const float*)d_in[8];
  const float* slopes = (const float*)d_in[9];

  char* ws = (char*)d_ws;
  u16* hsb = (u16*)(ws);                 // reused as ctx after QKV
  u16* wqb = (u16*)(ws + 33554432);      // wq|wk|wv contiguous => [6144][2048]
  u16* wkb = (u16*)(ws + 41943040);
  u16* wvb = (u16*)(ws + 50331648);
  u16* wob = (u16*)(ws + 58720256);
  u16* Qb  = (u16*)(ws + 67108864);
  u16* Kb  = (u16*)(ws + 100663296);
  u16* Vb  = (u16*)(ws + 134217728);
  u16* ctxb = hsb;

  convert_kernel<<<16384, 256, 0, stream>>>(hs, Wq, Wk, Wv, Wo, hsb, wqb, wkb,
                                            wvb, wob);
  gemm256_kernel<0><<<768, 512, 0, stream>>>(hsb, wqb, bq, bk, bv, Qb, Kb, Vb,
                                             32, 24);
  attn_kernel<<<512, 512, 0, stream>>>(Qb, Kb, Vb, slopes, ctxb);
  gemm256_kernel<1><<<256, 512, 0, stream>>>(ctxb, wob, bo, bo, bo, d_out,
                                             d_out, d_out, 32, 8);
}

// Round 11
// 472.818 us; speedup vs baseline: 1.4959x; 1.4959x over previous
//
#include <hip/hip_runtime.h>

typedef unsigned int u32;
typedef unsigned short u16;
typedef __bf16 bf16x8 __attribute__((ext_vector_type(8)));
typedef float f32x4 __attribute__((ext_vector_type(4)));
typedef float f32x2 __attribute__((ext_vector_type(2)));

// ---------- helpers ----------

__device__ __forceinline__ u16 f2bf(float f) {
  u32 u = __builtin_bit_cast(u32, f);
  u32 r = u + 0x7fffu + ((u >> 16) & 1u);  // RNE
  return (u16)(r >> 16);
}

__device__ __forceinline__ u32 cvtpk_bf16(float a, float b) {
  u32 d;
  asm("v_cvt_pk_bf16_f32 %0, %1, %2" : "=v"(d) : "v"(a), "v"(b));
  return d;  // lo = bf16(a), hi = bf16(b)
}

__device__ __forceinline__ void gload_lds16(const void* g, void* l) {
  __builtin_amdgcn_global_load_lds(
      (__attribute__((address_space(1))) void*)(g),
      (__attribute__((address_space(3))) void*)(l), 16, 0, 0);
}

// ---------- fp32 -> bf16 conversion (hs + 4 weights) ----------

__global__ __launch_bounds__(256) void convert_kernel(
    const float* __restrict__ hs, const float* __restrict__ wq,
    const float* __restrict__ wk, const float* __restrict__ wv,
    const float* __restrict__ wo,
    u16* __restrict__ hsb, u16* __restrict__ wqb, u16* __restrict__ wkb,
    u16* __restrict__ wvb, u16* __restrict__ wob) {
  long t = (long)blockIdx.x * 256 + threadIdx.x;
  const float* src;
  u16* dst;
  long off;
  if (t < 2097152) {
    src = hs; dst = hsb; off = t << 3;
  } else {
    long u = t - 2097152;
    int wi = (int)(u >> 19);
    off = (u & 524287) << 3;
    if (wi == 0)      { src = wq; dst = wqb; }
    else if (wi == 1) { src = wk; dst = wkb; }
    else if (wi == 2) { src = wv; dst = wvb; }
    else              { src = wo; dst = wob; }
  }
  float4 a = *(const float4*)(src + off);
  float4 b = *(const float4*)(src + off + 4);
  uint4 o;
  o.x = (u32)f2bf(a.x) | ((u32)f2bf(a.y) << 16);
  o.y = (u32)f2bf(a.z) | ((u32)f2bf(a.w) << 16);
  o.z = (u32)f2bf(b.x) | ((u32)f2bf(b.y) << 16);
  o.w = (u32)f2bf(b.z) | ((u32)f2bf(b.w) << 16);
  *(uint4*)(dst + off) = o;
}

// ---------- 256x256 GEMM, BK=64, 8 waves, read-ahead pipelined ----------
// (frozen: r5 schedule + r6 mapping v2)

template <int OF32>
__global__ __launch_bounds__(512, 2) void gemm256_kernel(
    const u16* __restrict__ A, const u16* __restrict__ Bw,
    const float* __restrict__ bias0, const float* __restrict__ bias1,
    const float* __restrict__ bias2, void* __restrict__ o0,
    void* __restrict__ o1, void* __restrict__ o2, int m_tiles, int n_tiles) {
  __shared__ __align__(16) char L[2][2][2][16384];  // [buf][op][khalf] 256r x 64B

  const int tid = threadIdx.x;
  const int lane = tid & 63, w = tid >> 6;
  const int lr = lane & 15, lk = lane >> 4;
  const int wm = (w >> 2) * 128, wn = (w & 3) * 64;

  const int bid = blockIdx.x;
  const int xcd = bid & 7, loc = bid >> 3;
  const int npx = n_tiles >> 3;
  const int n_idx = xcd * npx + loc % npx;
  const int m_idx = loc / npx;
  const int m0 = m_idx * 256, n0 = n_idx * 256;

  const char* Ab = (const char*)A;
  const char* Bb = (const char*)Bw;
  const char* gA[2];
  const char* gB[2];
#pragma unroll
  for (int j = 0; j < 2; j++) {
    const int o = j * 8192 + tid * 16;
    const int row = o >> 6;
    const int c = (o & 63) ^ (((row >> 1) & 3) << 4);
    gA[j] = Ab + (size_t)(m0 + row) * 4096 + c;
    gB[j] = Bb + (size_t)(n0 + row) * 4096 + c;
  }

  auto stage = [&](int t, int kh, int isB) {
    char* Ld = &L[t & 1][isB][kh][0] + tid * 16;
    const int gof = t * 128 + kh * 64;
#pragma unroll
    for (int j = 0; j < 2; j++)
      gload_lds16((isB ? gB[j] : gA[j]) + gof, Ld + j * 8192);
  };
  auto rdA = [&](bf16x8* dst, int buf, int kh, int mset) {
#pragma unroll
    for (int m = 0; m < 4; m++) {
      const int row = wm + mset * 64 + m * 16 + lr;
      const int c = (lk * 16) ^ (((row >> 1) & 3) << 4);
      dst[m] = *(const bf16x8*)(&L[buf][0][kh][0] + row * 64 + c);
    }
  };
  auto rdB = [&](bf16x8* dst, int buf, int kh) {
#pragma unroll
    for (int n = 0; n < 4; n++) {
      const int row = wn + n * 16 + lr;
      const int c = (lk * 16) ^ (((row >> 1) & 3) << 4);
      dst[n] = *(const bf16x8*)(&L[buf][1][kh][0] + row * 64 + c);
    }
  };

  f32x4 acc[2][4][4];
#pragma unroll
  for (int s = 0; s < 2; s++)
#pragma unroll
    for (int m = 0; m < 4; m++)
#pragma unroll
      for (int n = 0; n < 4; n++) acc[s][m][n] = {0.f, 0.f, 0.f, 0.f};

  auto mm = [&](f32x4 (&ac)[4][4], bf16x8* a_, bf16x8* b_) {
    __builtin_amdgcn_s_setprio(1);
#pragma unroll
    for (int m = 0; m < 4; m++)
#pragma unroll
      for (int n = 0; n < 4; n++)
        ac[m][n] = __builtin_amdgcn_mfma_f32_16x16x32_bf16(a_[m], b_[n],
                                                           ac[m][n], 0, 0, 0);
    __builtin_amdgcn_s_setprio(0);
  };

  // prologue: stage tile 0 fully (order kh0A, kh0B, kh1A, kh1B)
  stage(0, 0, 0); stage(0, 0, 1); stage(0, 1, 0); stage(0, 1, 1);

  bf16x8 aP[4], aQ[4], b0[4], b1[4];
  for (int t = 0; t < 32; ++t) {
    const int buf = t & 1;
    const int t1 = (t + 1 < 32) ? t + 1 : 31;
    // ===== segment A: {ph4(t-1) , ph1(t)} =====
    asm volatile("s_waitcnt vmcnt(4)" ::: "memory");  // publish (t,kh0,*)
    asm volatile("s_barrier" ::: "memory");
    rdA(aP, buf, 0, 0);            // ph1 operands
    rdB(b0, buf, 0);
    stage(t1, 0, 0);               // (t+1, kh0, A)
    if (t) mm(acc[1], aQ, b1);     // ph4(t-1): kh1 x mset1
    rdA(aQ, buf, 0, 1);            // ph2 operands
    stage(t1, 0, 1);               // (t+1, kh0, B)
    mm(acc[0], aP, b0);            // ph1: kh0 x mset0
    // ===== segment B: {ph2(t) , ph3(t)} =====
    asm volatile("s_waitcnt vmcnt(4)" ::: "memory");  // publish (t,kh1,*)
    asm volatile("s_barrier" ::: "memory");
    rdA(aP, buf, 1, 0);            // ph3 operands
    rdB(b1, buf, 1);
    stage(t1, 1, 0);               // (t+1, kh1, A)
    mm(acc[1], aQ, b0);            // ph2: kh0 x mset1
    rdA(aQ, buf, 1, 1);            // ph4 operands
    stage(t1, 1, 1);               // (t+1, kh1, B)
    mm(acc[0], aP, b1);            // ph3: kh1 x mset0
  }
  mm(acc[1], aQ, b1);              // ph4(31)

  // epilogue: bias + store
  const float* bias;
  void* op;
  int nl0;
  if (OF32) {
    bias = bias0; op = o0; nl0 = n0;
  } else {
    const int seg = n0 >> 11;
    bias = seg == 0 ? bias0 : (seg == 1 ? bias1 : bias2);
    op = seg == 0 ? o0 : (seg == 1 ? o1 : o2);
    nl0 = n0 & 2047;
  }
#pragma unroll
  for (int n = 0; n < 4; n++) {
    const int col = nl0 + wn + n * 16 + lr;
    const float bv = bias[col];
#pragma unroll
    for (int s = 0; s < 2; s++)
#pragma unroll
      for (int m = 0; m < 4; m++) {
        const int grow = m0 + wm + s * 64 + m * 16 + lk * 4;
#pragma unroll
        for (int r = 0; r < 4; r++) {
          const float v = acc[s][m][n][r] + bv;
          if (OF32)
            ((float*)op)[(size_t)(grow + r) * 2048 + col] = v;
          else
            ((u16*)op)[(size_t)(grow + r) * 2048 + col] = f2bf(v);
        }
      }
  }
}

// ---------- fused causal attention with alibi + tanh cap ----------
// v5b: v4 pipeline + packed-fp32 softmax (f32x2 -> v_pk_* ops) +
// v_cvt_pk_bf16_f32 P-pack. launch_bounds (512,2) — r10's (512,4) pinned
// VGPR to 64 and spilled ~1 GB to scratch (FETCH 49MB->1GB, 2.6x slower).

__global__ __launch_bounds__(512, 2) void attn_kernel(
    const u16* __restrict__ Qm, const u16* __restrict__ Km,
    const u16* __restrict__ Vm, const float* __restrict__ slopes,
    u16* __restrict__ ctx) {
  __shared__ __align__(16) char Ks[2][64 * 256];   // 32 KB, xor-swizzled rows
  __shared__ __align__(16) char Vt[128 * 128];     // 16 KB, V^T xor-swizzled
  __shared__ __align__(16) char Pb[8][16 * 128];   // 16 KB, per-wave P

  const int bid = blockIdx.x;
  const int sw = (bid & 7) * 64 + (bid >> 3);
  const int bh = sw >> 3, pi = sw & 7;
  const int b = bh >> 4, h = bh & 15;
  const int NTA = 2 * pi + 2;

  const int tid = threadIdx.x;
  const int lane = tid & 63, w = tid >> 6;
  const int lr = lane & 15, lk = lane >> 4;

  const char* Qb = (const char*)Qm + (size_t)b * 2048 * 4096 + h * 256;
  const char* Kb = (const char*)Km + (size_t)b * 2048 * 4096 + h * 256;
  const char* Vb = (const char*)Vm + (size_t)b * 2048 * 4096 + h * 256;

  const float SCALE = 0.08838834764831845f;  // 1/sqrt(128)
  const float sl_c = slopes[h] * SCALE;

  // odd poly for 30*tanh(z/30)*log2(e), |z|<=16
  const f32x2 C1v = {1.4426950408889634f, 1.4426950408889634f};
  const f32x2 C3v = {-5.343315e-4f, -5.343315e-4f};
  const f32x2 C5v = {2.374806e-7f, 2.374806e-7f};
  const f32x2 C7v = {-1.068005e-10f, -1.068005e-10f};
  const f32x2 SC2 = {SCALE, SCALE};
  const f32x2 NEG16 = {-16.0f, -16.0f};
  const f32x2 POS16 = {16.0f, 16.0f};

  // hoisted per-lane alibi offsets, paired over r: zo2[nb*2+p] for r=2p,2p+1
  f32x2 zo2[8];
#pragma unroll
  for (int nb = 0; nb < 4; nb++)
#pragma unroll
    for (int p = 0; p < 2; p++) {
      zo2[nb * 2 + p][0] = sl_c * (float)((lr - lk * 4) + nb * 16 - (2 * p));
      zo2[nb * 2 + p][1] = sl_c * (float)((lr - lk * 4) + nb * 16 - (2 * p + 1));
    }

  const int vd0 = (tid & 15) * 8;
  const int vkv2 = tid >> 4;

  uint4 vr0, vr1;

  auto kvt_of = [&](int it) { return it < NTA ? it : it - NTA; };

  auto stageK = [&](int it, int buf) {
    const int kv0 = kvt_of(it) * 64;
#pragma unroll
    for (int j = 0; j < 2; j++) {
      const int o = j * 8192 + tid * 16;
      const int row = o >> 8, c = (o & 255) ^ ((row & 7) << 4);
      gload_lds16(Kb + (size_t)(kv0 + row) * 4096 + c, Ks[buf] + o);
    }
  };
  auto loadV = [&](int it) {
    const int kv0 = kvt_of(it) * 64;
    vr0 = *(const uint4*)(Vb + (size_t)(kv0 + vkv2 * 2) * 4096 + vd0 * 2);
    vr1 = *(const uint4*)(Vb + (size_t)(kv0 + vkv2 * 2 + 1) * 4096 + vd0 * 2);
  };
  auto writeV = [&]() {
    const u32* p0 = (const u32*)&vr0;
    const u32* p1 = (const u32*)&vr1;
#pragma unroll
    for (int wd = 0; wd < 4; wd++) {
      const u32 ev = __builtin_amdgcn_perm(p1[wd], p0[wd], 0x05040100u);
      const u32 od = __builtin_amdgcn_perm(p1[wd], p0[wd], 0x07060302u);
      const int d0_ = vd0 + 2 * wd, d1_ = d0_ + 1;
      *(u32*)(Vt + d0_ * 128 +
              ((vkv2 * 4) ^ (((d0_ ^ (d0_ >> 3)) & 7) << 4))) = ev;
      *(u32*)(Vt + d1_ * 128 +
              ((vkv2 * 4) ^ (((d1_ ^ (d1_ >> 3)) & 7) << 4))) = od;
    }
  };

  bf16x8 qf[4];
  f32x4 pv[8];
  f32x2 rs2[2];
  int q0 = 0;

  stageK(0, 0);  // issued first (oldest in vmcnt FIFO)
  loadV(0);

  for (int it = 0; it < 34; ++it) {
    const int kb = it & 1;
    const int kv0 = kvt_of(it) * 64;

    if (it == 0 || it == NTA) {  // block-uniform: (re)load Q, reset acc
      const int st = (it == 0) ? pi : (15 - pi);
      q0 = st * 128 + w * 16;
#pragma unroll
      for (int kc = 0; kc < 4; kc++)
        qf[kc] =
            *(const bf16x8*)(Qb + (size_t)(q0 + lr) * 4096 + kc * 64 + lk * 16);
#pragma unroll
      for (int i = 0; i < 8; i++) pv[i] = {0.f, 0.f, 0.f, 0.f};
      rs2[0] = {0.f, 0.f};
      rs2[1] = {0.f, 0.f};
    }

    __syncthreads();  // A: all waves done with PV(it-1) reads of Vt
    writeV();
    asm volatile("s_waitcnt vmcnt(0)" ::: "memory");
    __syncthreads();  // B: publish Vt + Ks[kb]

    if (it + 1 < 34) {      // prefetch: K stage (full iter of flight) + V regs
      stageK(it + 1, kb ^ 1);
      loadV(it + 1);
    }

    // S = Q K^T   (reads Ks[kb])
    f32x4 sc[4];
    __builtin_amdgcn_s_setprio(1);
#pragma unroll
    for (int nb = 0; nb < 4; nb++) {
      f32x4 a = {0.f, 0.f, 0.f, 0.f};
      const int krow = nb * 16 + lr;
#pragma unroll
      for (int kc = 0; kc < 4; kc++) {
        const int off = krow * 256 + ((kc * 64 + lk * 16) ^ ((krow & 7) << 4));
        bf16x8 kf = *(const bf16x8*)(Ks[kb] + off);
        a = __builtin_amdgcn_mfma_f32_16x16x32_bf16(qf[kc], kf, a, 0, 0, 0);
      }
      sc[nb] = a;
    }
    __builtin_amdgcn_s_setprio(0);

    // softmax: packed-fp32 math, one exp2/element, mask only diagonal tiles
    const bool diag = (it < NTA) ? (it >= NTA - 2) : (it >= 32);
    const float sb = sl_c * (float)(kv0 - q0);
    const f32x2 sb2 = {sb, sb};
#pragma unroll
    for (int nb = 0; nb < 4; nb++) {
#pragma unroll
      for (int p = 0; p < 2; p++) {
        f32x2 s2 = {sc[nb][2 * p], sc[nb][2 * p + 1]};
        f32x2 z = __builtin_elementwise_fma(s2, SC2, zo2[nb * 2 + p] + sb2);
        z = __builtin_elementwise_max(z, NEG16);
        z = __builtin_elementwise_min(z, POS16);
        const f32x2 u2 = z * z;
        f32x2 hh = __builtin_elementwise_fma(u2, C7v, C5v);
        hh = __builtin_elementwise_fma(u2, hh, C3v);
        hh = __builtin_elementwise_fma(u2, hh, C1v);
        const f32x2 ee = z * hh;
        float p0 = exp2f(ee[0]);
        float p1 = exp2f(ee[1]);
        if (diag) {
          const int kv = kv0 + nb * 16 + lr;
          const int qA = q0 + lk * 4 + 2 * p;
          p0 = (kv <= qA) ? p0 : 0.0f;
          p1 = (kv <= qA + 1) ? p1 : 0.0f;
        }
        f32x2 pr = {p0, p1};
        rs2[p] += pr;
        const u32 pk = cvtpk_bf16(p0, p1);
        const int qq0 = lk * 4 + 2 * p;
        const int qq1 = qq0 + 1;
        const int off0 = qq0 * 128 + (((nb * 16 + lr) * 2) ^ ((qq0 & 7) << 4));
        const int off1 = qq1 * 128 + (((nb * 16 + lr) * 2) ^ ((qq1 & 7) << 4));
        *(u16*)(Pb[w] + off0) = (u16)pk;
        *(u16*)(Pb[w] + off1) = (u16)(pk >> 16);
      }
    }

    // ctx += P V   (reads Vt; closed by next iter's barrier A)
    __builtin_amdgcn_s_setprio(1);
#pragma unroll
    for (int kc = 0; kc < 2; kc++) {
      const int poff = lr * 128 + ((kc * 64 + lk * 16) ^ ((lr & 7) << 4));
      bf16x8 pf = *(const bf16x8*)(Pb[w] + poff);
#pragma unroll
      for (int db = 0; db < 8; db++) {
        const int d = db * 16 + lr;
        const int voff =
            d * 128 + ((kc * 64 + lk * 16) ^ (((d ^ (d >> 3)) & 7) << 4));
        bf16x8 vf = *(const bf16x8*)(Vt + voff);
        pv[db] = __builtin_amdgcn_mfma_f32_16x16x32_bf16(pf, vf, pv[db], 0, 0, 0);
      }
    }
    __builtin_amdgcn_s_setprio(0);

    if (it == NTA - 1 || it == 33) {  // finalize current supertile
      float inv[4];
#pragma unroll
      for (int r = 0; r < 4; r++) {
        float s = (r < 2) ? rs2[0][r & 1] : rs2[1][r & 1];
        s += __shfl_xor(s, 1);
        s += __shfl_xor(s, 2);
        s += __shfl_xor(s, 4);
        s += __shfl_xor(s, 8);
        inv[r] = 1.0f / s;
      }
      const size_t baserow = (size_t)b * 2048 + q0 + lk * 4;
#pragma unroll
      for (int db = 0; db < 8; db++)
#pragma unroll
        for (int r = 0; r < 4; r++)
          ctx[(baserow + r) * 2048 + h * 128 + db * 16 + lr] =
              f2bf(pv[db][r] * inv[r]);
    }
  }
}

// ---------- launcher ----------

extern "C" void kernel_launch(void* const* d_in, const int* in_sizes, int n_in,
                              void* d_out, int out_size, void* d_ws,
                              size_t ws_size, hipStream_t stream) {
  const float* hs = (const float*)d_in[0];
  const float* Wq = (const float*)d_in[1];
  const float* bq = (const float*)d_in[2];
  const float* Wk = (const float*)d_in[3];
  const float* bk = (const float*)d_in[4];
  const float* Wv = (const float*)d_in[5];
  const float* bv = (const float*)d_in[6];
  const float* Wo = (const float*)d_in[7];
  const float* bo = (const float*)d_in[8];
  const float* slopes = (const float*)d_in[9];

  char* ws = (char*)d_ws;
  u16* hsb = (u16*)(ws);                 // reused as ctx after QKV
  u16* wqb = (u16*)(ws + 33554432);      // wq|wk|wv contiguous => [6144][2048]
  u16* wkb = (u16*)(ws + 41943040);
  u16* wvb = (u16*)(ws + 50331648);
  u16* wob = (u16*)(ws + 58720256);
  u16* Qb  = (u16*)(ws + 67108864);
  u16* Kb  = (u16*)(ws + 100663296);
  u16* Vb  = (u16*)(ws + 134217728);
  u16* ctxb = hsb;

  convert_kernel<<<16384, 256, 0, stream>>>(hs, Wq, Wk, Wv, Wo, hsb, wqb, wkb,
                                            wvb, wob);
  gemm256_kernel<0><<<768, 512, 0, stream>>>(hsb, wqb, bq, bk, bv, Qb, Kb, Vb,
                                             32, 24);
  attn_kernel<<<512, 512, 0, stream>>>(Qb, Kb, Vb, slopes, ctxb);
  gemm256_kernel<1><<<256, 512, 0, stream>>>(ctxb, wob, bo, bo, bo, d_out,
                                             d_out, d_out, 32, 8);
}

// Round 12
// 449.631 us; speedup vs baseline: 1.5730x; 1.0516x over previous
//
#include <hip/hip_runtime.h>

typedef unsigned int u32;
typedef unsigned short u16;
typedef __bf16 bf16x8 __attribute__((ext_vector_type(8)));
typedef float f32x4 __attribute__((ext_vector_type(4)));
typedef float f32x2 __attribute__((ext_vector_type(2)));

// ---------- helpers ----------

__device__ __forceinline__ u16 f2bf(float f) {
  u32 u = __builtin_bit_cast(u32, f);
  u32 r = u + 0x7fffu + ((u >> 16) & 1u);  // RNE
  return (u16)(r >> 16);
}

__device__ __forceinline__ u32 cvtpk_bf16(float a, float b) {
  u32 d;
  asm("v_cvt_pk_bf16_f32 %0, %1, %2" : "=v"(d) : "v"(a), "v"(b));
  return d;  // lo = bf16(a), hi = bf16(b)
}

__device__ __forceinline__ void gload_lds16(const void* g, void* l) {
  __builtin_amdgcn_global_load_lds(
      (__attribute__((address_space(1))) void*)(g),
      (__attribute__((address_space(3))) void*)(l), 16, 0, 0);
}

// ---------- fp32 -> bf16 conversion (hs + 4 weights) ----------

__global__ __launch_bounds__(256) void convert_kernel(
    const float* __restrict__ hs, const float* __restrict__ wq,
    const float* __restrict__ wk, const float* __restrict__ wv,
    const float* __restrict__ wo,
    u16* __restrict__ hsb, u16* __restrict__ wqb, u16* __restrict__ wkb,
    u16* __restrict__ wvb, u16* __restrict__ wob) {
  long t = (long)blockIdx.x * 256 + threadIdx.x;
  const float* src;
  u16* dst;
  long off;
  if (t < 2097152) {
    src = hs; dst = hsb; off = t << 3;
  } else {
    long u = t - 2097152;
    int wi = (int)(u >> 19);
    off = (u & 524287) << 3;
    if (wi == 0)      { src = wq; dst = wqb; }
    else if (wi == 1) { src = wk; dst = wkb; }
    else if (wi == 2) { src = wv; dst = wvb; }
    else              { src = wo; dst = wob; }
  }
  float4 a = *(const float4*)(src + off);
  float4 b = *(const float4*)(src + off + 4);
  uint4 o;
  o.x = (u32)f2bf(a.x) | ((u32)f2bf(a.y) << 16);
  o.y = (u32)f2bf(a.z) | ((u32)f2bf(a.w) << 16);
  o.z = (u32)f2bf(b.x) | ((u32)f2bf(b.y) << 16);
  o.w = (u32)f2bf(b.z) | ((u32)f2bf(b.w) << 16);
  *(uint4*)(dst + off) = o;
}

// ---------- 256x256 GEMM, BK=64, 8 waves, read-ahead pipelined ----------
// (frozen: r5 schedule + r6 mapping v2)

template <int OF32>
__global__ __launch_bounds__(512, 2) void gemm256_kernel(
    const u16* __restrict__ A, const u16* __restrict__ Bw,
    const float* __restrict__ bias0, const float* __restrict__ bias1,
    const float* __restrict__ bias2, void* __restrict__ o0,
    void* __restrict__ o1, void* __restrict__ o2, int m_tiles, int n_tiles) {
  __shared__ __align__(16) char L[2][2][2][16384];  // [buf][op][khalf] 256r x 64B

  const int tid = threadIdx.x;
  const int lane = tid & 63, w = tid >> 6;
  const int lr = lane & 15, lk = lane >> 4;
  const int wm = (w >> 2) * 128, wn = (w & 3) * 64;

  const int bid = blockIdx.x;
  const int xcd = bid & 7, loc = bid >> 3;
  const int npx = n_tiles >> 3;
  const int n_idx = xcd * npx + loc % npx;
  const int m_idx = loc / npx;
  const int m0 = m_idx * 256, n0 = n_idx * 256;

  const char* Ab = (const char*)A;
  const char* Bb = (const char*)Bw;
  const char* gA[2];
  const char* gB[2];
#pragma unroll
  for (int j = 0; j < 2; j++) {
    const int o = j * 8192 + tid * 16;
    const int row = o >> 6;
    const int c = (o & 63) ^ (((row >> 1) & 3) << 4);
    gA[j] = Ab + (size_t)(m0 + row) * 4096 + c;
    gB[j] = Bb + (size_t)(n0 + row) * 4096 + c;
  }

  auto stage = [&](int t, int kh, int isB) {
    char* Ld = &L[t & 1][isB][kh][0] + tid * 16;
    const int gof = t * 128 + kh * 64;
#pragma unroll
    for (int j = 0; j < 2; j++)
      gload_lds16((isB ? gB[j] : gA[j]) + gof, Ld + j * 8192);
  };
  auto rdA = [&](bf16x8* dst, int buf, int kh, int mset) {
#pragma unroll
    for (int m = 0; m < 4; m++) {
      const int row = wm + mset * 64 + m * 16 + lr;
      const int c = (lk * 16) ^ (((row >> 1) & 3) << 4);
      dst[m] = *(const bf16x8*)(&L[buf][0][kh][0] + row * 64 + c);
    }
  };
  auto rdB = [&](bf16x8* dst, int buf, int kh) {
#pragma unroll
    for (int n = 0; n < 4; n++) {
      const int row = wn + n * 16 + lr;
      const int c = (lk * 16) ^ (((row >> 1) & 3) << 4);
      dst[n] = *(const bf16x8*)(&L[buf][1][kh][0] + row * 64 + c);
    }
  };

  f32x4 acc[2][4][4];
#pragma unroll
  for (int s = 0; s < 2; s++)
#pragma unroll
    for (int m = 0; m < 4; m++)
#pragma unroll
      for (int n = 0; n < 4; n++) acc[s][m][n] = {0.f, 0.f, 0.f, 0.f};

  auto mm = [&](f32x4 (&ac)[4][4], bf16x8* a_, bf16x8* b_) {
    __builtin_amdgcn_s_setprio(1);
#pragma unroll
    for (int m = 0; m < 4; m++)
#pragma unroll
      for (int n = 0; n < 4; n++)
        ac[m][n] = __builtin_amdgcn_mfma_f32_16x16x32_bf16(a_[m], b_[n],
                                                           ac[m][n], 0, 0, 0);
    __builtin_amdgcn_s_setprio(0);
  };

  // prologue: stage tile 0 fully (order kh0A, kh0B, kh1A, kh1B)
  stage(0, 0, 0); stage(0, 0, 1); stage(0, 1, 0); stage(0, 1, 1);

  bf16x8 aP[4], aQ[4], b0[4], b1[4];
  for (int t = 0; t < 32; ++t) {
    const int buf = t & 1;
    const int t1 = (t + 1 < 32) ? t + 1 : 31;
    // ===== segment A: {ph4(t-1) , ph1(t)} =====
    asm volatile("s_waitcnt vmcnt(4)" ::: "memory");  // publish (t,kh0,*)
    asm volatile("s_barrier" ::: "memory");
    rdA(aP, buf, 0, 0);            // ph1 operands
    rdB(b0, buf, 0);
    stage(t1, 0, 0);               // (t+1, kh0, A)
    if (t) mm(acc[1], aQ, b1);     // ph4(t-1): kh1 x mset1
    rdA(aQ, buf, 0, 1);            // ph2 operands
    stage(t1, 0, 1);               // (t+1, kh0, B)
    mm(acc[0], aP, b0);            // ph1: kh0 x mset0
    // ===== segment B: {ph2(t) , ph3(t)} =====
    asm volatile("s_waitcnt vmcnt(4)" ::: "memory");  // publish (t,kh1,*)
    asm volatile("s_barrier" ::: "memory");
    rdA(aP, buf, 1, 0);            // ph3 operands
    rdB(b1, buf, 1);
    stage(t1, 1, 0);               // (t+1, kh1, A)
    mm(acc[1], aQ, b0);            // ph2: kh0 x mset1
    rdA(aQ, buf, 1, 1);            // ph4 operands
    stage(t1, 1, 1);               // (t+1, kh1, B)
    mm(acc[0], aP, b1);            // ph3: kh1 x mset0
  }
  mm(acc[1], aQ, b1);              // ph4(31)

  // epilogue: bias + store
  const float* bias;
  void* op;
  int nl0;
  if (OF32) {
    bias = bias0; op = o0; nl0 = n0;
  } else {
    const int seg = n0 >> 11;
    bias = seg == 0 ? bias0 : (seg == 1 ? bias1 : bias2);
    op = seg == 0 ? o0 : (seg == 1 ? o1 : o2);
    nl0 = n0 & 2047;
  }
#pragma unroll
  for (int n = 0; n < 4; n++) {
    const int col = nl0 + wn + n * 16 + lr;
    const float bv = bias[col];
#pragma unroll
    for (int s = 0; s < 2; s++)
#pragma unroll
      for (int m = 0; m < 4; m++) {
        const int grow = m0 + wm + s * 64 + m * 16 + lk * 4;
#pragma unroll
        for (int r = 0; r < 4; r++) {
          const float v = acc[s][m][n][r] + bv;
          if (OF32)
            ((float*)op)[(size_t)(grow + r) * 2048 + col] = v;
          else
            ((u16*)op)[(size_t)(grow + r) * 2048 + col] = f2bf(v);
        }
      }
  }
}

// ---------- fused causal attention with alibi + tanh cap ----------
// v6: 32 q-rows/wave (256/block), 256 blocks (1/CU), 80 KB LDS. K and V
// fragments are read from LDS ONCE and reused for both 16-row halves (mi)
// -> 36 b128 reads per 32 MFMA (halved LDS traffic per FLOP vs v5).
// Supertile pairs (pi, 7-pi): uniform 36 iters. v4 pipeline + pk-softmax.

__global__ __launch_bounds__(512, 2) void attn_kernel(
    const u16* __restrict__ Qm, const u16* __restrict__ Km,
    const u16* __restrict__ Vm, const float* __restrict__ slopes,
    u16* __restrict__ ctx) {
  __shared__ __align__(16) char Ks[2][64 * 256];   // 32 KB, xor-swizzled rows
  __shared__ __align__(16) char Vt[128 * 128];     // 16 KB, V^T xor-swizzled
  __shared__ __align__(16) char Pb[8][32 * 128];   // 32 KB, per-wave P (32 q)

  const int bid = blockIdx.x;                      // 0..255
  const int sw = (bid & 7) * 32 + (bid >> 3);      // XCD-contiguous heads
  const int bh = sw >> 2, pi = sw & 3;
  const int b = bh >> 4, h = bh & 15;
  const int NTA = 4 * pi + 4;                      // iters for supertile A

  const int tid = threadIdx.x;
  const int lane = tid & 63, w = tid >> 6;
  const int lr = lane & 15, lk = lane >> 4;

  const char* Qb = (const char*)Qm + (size_t)b * 2048 * 4096 + h * 256;
  const char* Kb = (const char*)Km + (size_t)b * 2048 * 4096 + h * 256;
  const char* Vb = (const char*)Vm + (size_t)b * 2048 * 4096 + h * 256;

  const float SCALE = 0.08838834764831845f;  // 1/sqrt(128)
  const float sl_c = slopes[h] * SCALE;

  // odd poly for 30*tanh(z/30)*log2(e), |z|<=16
  const f32x2 C1v = {1.4426950408889634f, 1.4426950408889634f};
  const f32x2 C3v = {-5.343315e-4f, -5.343315e-4f};
  const f32x2 C5v = {2.374806e-7f, 2.374806e-7f};
  const f32x2 C7v = {-1.068005e-10f, -1.068005e-10f};
  const f32x2 SC2 = {SCALE, SCALE};
  const f32x2 NEG16 = {-16.0f, -16.0f};
  const f32x2 POS16 = {16.0f, 16.0f};

  // hoisted per-lane alibi offsets, paired over r: zo2[nb*2+p] for r=2p,2p+1
  f32x2 zo2[8];
#pragma unroll
  for (int nb = 0; nb < 4; nb++)
#pragma unroll
    for (int p = 0; p < 2; p++) {
      zo2[nb * 2 + p][0] = sl_c * (float)((lr - lk * 4) + nb * 16 - (2 * p));
      zo2[nb * 2 + p][1] = sl_c * (float)((lr - lk * 4) + nb * 16 - (2 * p + 1));
    }

  const int vd0 = (tid & 15) * 8;
  const int vkv2 = tid >> 4;

  uint4 vr0, vr1;

  auto kvt_of = [&](int it) { return it < NTA ? it : it - NTA; };

  auto stageK = [&](int it, int buf) {
    const int kv0 = kvt_of(it) * 64;
#pragma unroll
    for (int j = 0; j < 2; j++) {
      const int o = j * 8192 + tid * 16;
      const int row = o >> 8, c = (o & 255) ^ ((row & 7) << 4);
      gload_lds16(Kb + (size_t)(kv0 + row) * 4096 + c, Ks[buf] + o);
    }
  };
  auto loadV = [&](int it) {
    const int kv0 = kvt_of(it) * 64;
    vr0 = *(const uint4*)(Vb + (size_t)(kv0 + vkv2 * 2) * 4096 + vd0 * 2);
    vr1 = *(const uint4*)(Vb + (size_t)(kv0 + vkv2 * 2 + 1) * 4096 + vd0 * 2);
  };
  auto writeV = [&]() {
    const u32* p0 = (const u32*)&vr0;
    const u32* p1 = (const u32*)&vr1;
#pragma unroll
    for (int wd = 0; wd < 4; wd++) {
      const u32 ev = __builtin_amdgcn_perm(p1[wd], p0[wd], 0x05040100u);
      const u32 od = __builtin_amdgcn_perm(p1[wd], p0[wd], 0x07060302u);
      const int d0_ = vd0 + 2 * wd, d1_ = d0_ + 1;
      *(u32*)(Vt + d0_ * 128 +
              ((vkv2 * 4) ^ (((d0_ ^ (d0_ >> 3)) & 7) << 4))) = ev;
      *(u32*)(Vt + d1_ * 128 +
              ((vkv2 * 4) ^ (((d1_ ^ (d1_ >> 3)) & 7) << 4))) = od;
    }
  };

  bf16x8 qf[2][4];
  f32x4 pv[2][8];
  f32x2 rs2[2][2];
  int q0 = 0;

  stageK(0, 0);  // issued first (oldest in vmcnt FIFO)
  loadV(0);

  for (int it = 0; it < 36; ++it) {
    const int kb = it & 1;
    const int kv0 = kvt_of(it) * 64;

    if (it == 0 || it == NTA) {  // block-uniform: (re)load Q, reset acc
      const int st = (it == 0) ? pi : (7 - pi);
      q0 = st * 256 + w * 32;
#pragma unroll
      for (int mi = 0; mi < 2; mi++)
#pragma unroll
        for (int kc = 0; kc < 4; kc++)
          qf[mi][kc] = *(const bf16x8*)(Qb + (size_t)(q0 + mi * 16 + lr) * 4096 +
                                        kc * 64 + lk * 16);
#pragma unroll
      for (int mi = 0; mi < 2; mi++) {
#pragma unroll
        for (int i = 0; i < 8; i++) pv[mi][i] = {0.f, 0.f, 0.f, 0.f};
        rs2[mi][0] = {0.f, 0.f};
        rs2[mi][1] = {0.f, 0.f};
      }
    }

    __syncthreads();  // A: all waves done with PV(it-1) reads of Vt
    writeV();         // waits on vr loads (issued after stageK(it) in FIFO)
    asm volatile("s_waitcnt vmcnt(0)" ::: "memory");
    __syncthreads();  // B: publish Vt + Ks[kb]

    if (it + 1 < 36) {  // prefetch: K stage (full iter of flight) + V regs
      stageK(it + 1, kb ^ 1);
      loadV(it + 1);
    }

    // S = Q K^T : K-frags read once, used for both mi halves
    f32x4 sc[2][4];
    __builtin_amdgcn_s_setprio(1);
#pragma unroll
    for (int nb = 0; nb < 4; nb++) {
      const int krow = nb * 16 + lr;
      bf16x8 kf[4];
#pragma unroll
      for (int kc = 0; kc < 4; kc++) {
        const int off = krow * 256 + ((kc * 64 + lk * 16) ^ ((krow & 7) << 4));
        kf[kc] = *(const bf16x8*)(Ks[kb] + off);
      }
#pragma unroll
      for (int mi = 0; mi < 2; mi++) {
        f32x4 a = {0.f, 0.f, 0.f, 0.f};
#pragma unroll
        for (int kc = 0; kc < 4; kc++)
          a = __builtin_amdgcn_mfma_f32_16x16x32_bf16(qf[mi][kc], kf[kc], a, 0,
                                                      0, 0);
        sc[mi][nb] = a;
      }
    }
    __builtin_amdgcn_s_setprio(0);

    // softmax: packed-fp32 math; mask only last-4 (diagonal) iters/supertile
    const bool diag = (it < NTA) ? (it >= NTA - 4) : (it >= 32);
    const float sb = sl_c * (float)(kv0 - q0);
#pragma unroll
    for (int mi = 0; mi < 2; mi++) {
      const float sbm = sb - sl_c * (float)(16 * mi);
      const f32x2 sb2 = {sbm, sbm};
#pragma unroll
      for (int nb = 0; nb < 4; nb++) {
#pragma unroll
        for (int p = 0; p < 2; p++) {
          f32x2 s2 = {sc[mi][nb][2 * p], sc[mi][nb][2 * p + 1]};
          f32x2 z = __builtin_elementwise_fma(s2, SC2, zo2[nb * 2 + p] + sb2);
          z = __builtin_elementwise_max(z, NEG16);
          z = __builtin_elementwise_min(z, POS16);
          const f32x2 u2 = z * z;
          f32x2 hh = __builtin_elementwise_fma(u2, C7v, C5v);
          hh = __builtin_elementwise_fma(u2, hh, C3v);
          hh = __builtin_elementwise_fma(u2, hh, C1v);
          const f32x2 ee = z * hh;
          float p0 = exp2f(ee[0]);
          float p1 = exp2f(ee[1]);
          if (diag) {
            const int kv = kv0 + nb * 16 + lr;
            const int qA = q0 + mi * 16 + lk * 4 + 2 * p;
            p0 = (kv <= qA) ? p0 : 0.0f;
            p1 = (kv <= qA + 1) ? p1 : 0.0f;
          }
          f32x2 pr = {p0, p1};
          rs2[mi][p] += pr;
          const u32 pk = cvtpk_bf16(p0, p1);
          const int qq0 = mi * 16 + lk * 4 + 2 * p;
          const int qq1 = qq0 + 1;
          const int off0 =
              qq0 * 128 + (((nb * 16 + lr) * 2) ^ ((qq0 & 7) << 4));
          const int off1 =
              qq1 * 128 + (((nb * 16 + lr) * 2) ^ ((qq1 & 7) << 4));
          *(u16*)(Pb[w] + off0) = (u16)pk;
          *(u16*)(Pb[w] + off1) = (u16)(pk >> 16);
        }
      }
    }

    // ctx += P V : V-frags read once, used for both mi halves
    __builtin_amdgcn_s_setprio(1);
#pragma unroll
    for (int kc = 0; kc < 2; kc++) {
      bf16x8 pf[2];
#pragma unroll
      for (int mi = 0; mi < 2; mi++) {
        const int prow = mi * 16 + lr;
        const int poff =
            prow * 128 + ((kc * 64 + lk * 16) ^ ((lr & 7) << 4));
        pf[mi] = *(const bf16x8*)(Pb[w] + poff);
      }
#pragma unroll
      for (int db = 0; db < 8; db++) {
        const int d = db * 16 + lr;
        const int voff =
            d * 128 + ((kc * 64 + lk * 16) ^ (((d ^ (d >> 3)) & 7) << 4));
        bf16x8 vf = *(const bf16x8*)(Vt + voff);
#pragma unroll
        for (int mi = 0; mi < 2; mi++)
          pv[mi][db] = __builtin_amdgcn_mfma_f32_16x16x32_bf16(pf[mi], vf,
                                                               pv[mi][db], 0,
                                                               0, 0);
      }
    }
    __builtin_amdgcn_s_setprio(0);

    if (it == NTA - 1 || it == 35) {  // finalize current supertile
#pragma unroll
      for (int mi = 0; mi < 2; mi++) {
        float inv[4];
#pragma unroll
        for (int r = 0; r < 4; r++) {
          float s = (r < 2) ? rs2[mi][0][r & 1] : rs2[mi][1][r & 1];
          s += __shfl_xor(s, 1);
          s += __shfl_xor(s, 2);
          s += __shfl_xor(s, 4);
          s += __shfl_xor(s, 8);
          inv[r] = 1.0f / s;
        }
        const size_t baserow = (size_t)b * 2048 + q0 + mi * 16 + lk * 4;
#pragma unroll
        for (int db = 0; db < 8; db++)
#pragma unroll
          for (int r = 0; r < 4; r++)
            ctx[(baserow + r) * 2048 + h * 128 + db * 16 + lr] =
                f2bf(pv[mi][db][r] * inv[r]);
      }
    }
  }
}

// ---------- launcher ----------

extern "C" void kernel_launch(void* const* d_in, const int* in_sizes, int n_in,
                              void* d_out, int out_size, void* d_ws,
                              size_t ws_size, hipStream_t stream) {
  const float* hs = (const float*)d_in[0];
  const float* Wq = (const float*)d_in[1];
  const float* bq = (const float*)d_in[2];
  const float* Wk = (const float*)d_in[3];
  const float* bk = (const float*)d_in[4];
  const float* Wv = (const float*)d_in[5];
  const float* bv = (const float*)d_in[6];
  const float* Wo = (const float*)d_in[7];
  const float* bo = (const float*)d_in[8];
  const float* slopes = (const float*)d_in[9];

  char* ws = (char*)d_ws;
  u16* hsb = (u16*)(ws);                 // reused as ctx after QKV
  u16* wqb = (u16*)(ws + 33554432);      // wq|wk|wv contiguous => [6144][2048]
  u16* wkb = (u16*)(ws + 41943040);
  u16* wvb = (u16*)(ws + 50331648);
  u16* wob = (u16*)(ws + 58720256);
  u16* Qb  = (u16*)(ws + 67108864);
  u16* Kb  = (u16*)(ws + 100663296);
  u16* Vb  = (u16*)(ws + 134217728);
  u16* ctxb = hsb;

  convert_kernel<<<16384, 256, 0, stream>>>(hs, Wq, Wk, Wv, Wo, hsb, wqb, wkb,
                                            wvb, wob);
  gemm256_kernel<0><<<768, 512, 0, stream>>>(hsb, wqb, bq, bk, bv, Qb, Kb, Vb,
                                             32, 24);
  attn_kernel<<<256, 512, 0, stream>>>(Qb, Kb, Vb, slopes, ctxb);
  gemm256_kernel<1><<<256, 512, 0, stream>>>(ctxb, wob, bo, bo, bo, d_out,
                                             d_out, d_out, 32, 8);
}